// Round 1
// 4472.810 us; speedup vs baseline: 1.0015x; 1.0015x over previous
//
#include <hip/hip_runtime.h>
#include <cstdint>
#include <cstddef>

#define BATCH 16384

typedef float f32x4 __attribute__((ext_vector_type(4)));
typedef _Float16 f16x8 __attribute__((ext_vector_type(8)));

__device__ __forceinline__ unsigned short f2h_bits(float f) {
  _Float16 h = (_Float16)f;
  return __builtin_bit_cast(unsigned short, h);
}

__device__ __forceinline__ void async_cp16(const void* g, void* l) {
  __builtin_amdgcn_global_load_lds(
      (const __attribute__((address_space(1))) unsigned int*)g,
      (__attribute__((address_space(3))) unsigned int*)l, 16, 0, 0);
}

// Barrier WITHOUT the full vmcnt(0) drain __syncthreads would force.
#define PIPE_BAR_3() asm volatile("s_waitcnt vmcnt(3)\n\ts_barrier" ::: "memory")
#define PIPE_BAR_0() asm volatile("s_waitcnt vmcnt(0)\n\ts_barrier" ::: "memory")

// ---------------------------------------------------------------------------
// Hidden-layer GEMM, small-K case (layer 0 only now): R6/R7 proven kernel.
// ---------------------------------------------------------------------------
template <int BM, int BN, int RT, int CT, int K, int N, bool RELU>
__launch_bounds__(512, 4)
__global__ void gemm_h(const unsigned short* __restrict__ A,
                       const unsigned short* __restrict__ Bw,
                       const float* __restrict__ Wfull,
                       const float* __restrict__ bias,
                       float tval,
                       unsigned short* __restrict__ Ch) {
  constexpr int BK = 32;
  constexpr int NI = K / BK;
  static_assert(NI >= 2, "pipeline needs >=2 stages");
  static_assert((BM * 4 + BN * 4) / 512 == 3, "vmcnt(3) assumes 3 loads/stage");
  static_assert(BM == 4 * RT * 16 && BN == 2 * CT * 16, "4x2 waves");
  __shared__ __align__(16) unsigned short smA[3][BM * BK];
  __shared__ __align__(16) unsigned short smB[3][BN * BK];
  __shared__ float biasLds[BN];

  const int tid = threadIdx.x;
  const int wave = tid >> 6;
  const int lane = tid & 63;
  const int quad = lane >> 4;
  const int r16 = lane & 15;

  const int rowA0 = blockIdx.x * BM;
  const int rowB0 = blockIdx.y * BN;
  const int waveM = wave >> 1;
  const int waveN = wave & 1;

  if (tid < BN) {
    const int col = rowB0 + tid;
    biasLds[tid] = bias[col] + tval * Wfull[(size_t)col * (K + 1) + K];
  }

  auto stage = [&](int k0, int buf) {
#pragma unroll
    for (int i = 0; i < BM * 4 / 512; ++i) {
      const int s = i * 512 + tid;
      const int row = s >> 2;
      const int c = (s & 3) ^ ((row >> 1) & 3);
      const unsigned short* g = A + (size_t)(rowA0 + row) * K + (k0 + c * 8);
      char* l = ((char*)smA[buf]) + (size_t)(i * 512 + (wave << 6)) * 16;
      async_cp16(g, l);
    }
    {
      const int s = tid;
      const int row = s >> 2;
      const int c = (s & 3) ^ ((row >> 1) & 3);
      const unsigned short* g = Bw + (size_t)(rowB0 + row) * K + (k0 + c * 8);
      char* l = ((char*)smB[buf]) + (size_t)((wave << 6)) * 16;
      async_cp16(g, l);
    }
  };

  f32x4 acc[RT][CT];
  const f32x4 zero = {0.f, 0.f, 0.f, 0.f};
#pragma unroll
  for (int i = 0; i < RT; ++i)
#pragma unroll
    for (int j = 0; j < CT; ++j) acc[i][j] = zero;

  auto compute = [&](int buf) {
    const unsigned short* sA = smA[buf];
    const unsigned short* sB = smB[buf];
    f16x8 af[RT], bfr[CT];
#pragma unroll
    for (int nt = 0; nt < CT; ++nt) {
      const int row = waveN * (CT * 16) + nt * 16 + r16;
      const int cp = quad ^ ((row >> 1) & 3);
      bfr[nt] = *(const f16x8*)(sB + row * BK + cp * 8);
    }
#pragma unroll
    for (int mt = 0; mt < RT; ++mt) {
      const int row = waveM * (RT * 16) + mt * 16 + r16;
      const int cp = quad ^ ((row >> 1) & 3);
      af[mt] = *(const f16x8*)(sA + row * BK + cp * 8);
    }
#pragma unroll
    for (int mt = 0; mt < RT; ++mt)
#pragma unroll
      for (int nt = 0; nt < CT; ++nt)
        acc[mt][nt] =
            __builtin_amdgcn_mfma_f32_16x16x32_f16(af[mt], bfr[nt], acc[mt][nt], 0, 0, 0);
  };

  stage(0, 0);
  stage(BK, 1);

#pragma unroll
  for (int kk = 0; kk < NI - 1; ++kk) {
    PIPE_BAR_3();
    if (kk + 2 < NI) stage((kk + 2) * BK, (kk + 2) % 3);
    compute(kk % 3);
  }
  PIPE_BAR_0();
  compute((NI - 1) % 3);

#pragma unroll
  for (int mt = 0; mt < RT; ++mt) {
    const int grow0 = rowA0 + waveM * (RT * 16) + mt * 16 + quad * 4;
#pragma unroll
    for (int nt = 0; nt < CT; ++nt) {
      const int lcol = waveN * (CT * 16) + nt * 16 + r16;
      const int gcol = rowB0 + lcol;
      const float bi = biasLds[lcol];
#pragma unroll
      for (int r = 0; r < 4; ++r) {
        float v = acc[mt][nt][r] + bi;
        if (RELU) v = fmaxf(v, 0.0f);
        Ch[(size_t)(grow0 + r) * N + gcol] = f2h_bits(v);
      }
    }
  }
}

// ---------------------------------------------------------------------------
// Big-GEMM (K=N=1024): 256x256 tile, BK=64, 8 waves (2x4), per-wave 128x64,
// 4 phases per K-tile (8 per double-buffer pair), counted vmcnt(8) at tile
// boundaries only, setprio(1) around each 16-MFMA cluster.
//
// Staging safety (race-analyzed): stage slots sit AFTER the mid-phase
// {lgkmcnt(0); s_barrier}, and target only LDS regions whose LAST ds_read for
// the current tile happened at-or-before that barrier:
//   q0: stage B-half0(t+2)  (all bfr of tile t read in q0, pre-barrier)
//   q1: stage B-half1(t+2)
//   q3: stage A-half0+A-half1(t+2) (A slice q read at phase q; all done by q3)
// Tile boundary: s_waitcnt vmcnt(8) -> the 8 loads of tile t+2 stay in flight,
// everything older (tile t+1, opposite buffer) has landed; barrier publishes.
// LDS swizzle: chunk' = chunk ^ (row&7) (8x16B chunks/row, stride 128B) ->
// within each 16-lane service group reads spread over 8 chunk-cols, 2-way max.
// Pre-swizzled global source keeps global_load_lds destinations linear.
// ---------------------------------------------------------------------------
#define SBAR  asm volatile("s_barrier" ::: "memory")
#define MBAR  asm volatile("s_waitcnt lgkmcnt(0)\n\ts_barrier" ::: "memory")
#define VBAR8 asm volatile("s_waitcnt vmcnt(8)\n\ts_barrier" ::: "memory")
#define VBAR0 asm volatile("s_waitcnt vmcnt(0)\n\ts_barrier" ::: "memory")

#define PHASE(sA_, sB_, Q, STAGE_STMT, BND)                                   \
  {                                                                           \
    if ((Q) == 0) {                                                           \
      _Pragma("unroll") for (int nt = 0; nt < 4; ++nt) {                      \
        const int row = wc * 64 + nt * 16 + r16;                              \
        const int sw = row & 7;                                               \
        const unsigned short* bp = (sB_) + row * 64;                          \
        bfr[nt][0] = *(const f16x8*)(bp + ((quad ^ sw) << 3));                \
        bfr[nt][1] = *(const f16x8*)(bp + (((4 + quad) ^ sw) << 3));          \
      }                                                                       \
    }                                                                         \
    f16x8 af0[2], af1[2];                                                     \
    _Pragma("unroll") for (int mi = 0; mi < 2; ++mi) {                        \
      const int row = wr * 128 + ((Q) * 2 + mi) * 16 + r16;                   \
      const int sw = row & 7;                                                 \
      const unsigned short* ap = (sA_) + row * 64;                            \
      af0[mi] = *(const f16x8*)(ap + ((quad ^ sw) << 3));                     \
      af1[mi] = *(const f16x8*)(ap + (((4 + quad) ^ sw) << 3));               \
    }                                                                         \
    MBAR;                                                                     \
    STAGE_STMT;                                                               \
    __builtin_amdgcn_s_setprio(1);                                            \
    _Pragma("unroll") for (int mi = 0; mi < 2; ++mi)                          \
      _Pragma("unroll") for (int nt = 0; nt < 4; ++nt) {                      \
        acc[(Q) * 2 + mi][nt] = __builtin_amdgcn_mfma_f32_16x16x32_f16(       \
            af0[mi], bfr[nt][0], acc[(Q) * 2 + mi][nt], 0, 0, 0);             \
        acc[(Q) * 2 + mi][nt] = __builtin_amdgcn_mfma_f32_16x16x32_f16(       \
            af1[mi], bfr[nt][1], acc[(Q) * 2 + mi][nt], 0, 0, 0);             \
      }                                                                       \
    __builtin_amdgcn_s_setprio(0);                                            \
    BND;                                                                      \
  }

#define TILE(sA_, sB_, STG0, STG1, STG3, BND)  \
  {                                            \
    f16x8 bfr[4][2];                           \
    PHASE(sA_, sB_, 0, STG0, SBAR)             \
    PHASE(sA_, sB_, 1, STG1, SBAR)             \
    PHASE(sA_, sB_, 2, ;, SBAR)                \
    PHASE(sA_, sB_, 3, STG3, BND)              \
  }

__launch_bounds__(512, 2)
__global__ void gemm8(const unsigned short* __restrict__ A,
                      const unsigned short* __restrict__ Bw,
                      const float* __restrict__ Wfull,
                      const float* __restrict__ bias,
                      float tval,
                      unsigned short* __restrict__ Ch) {
  // LDS: 2 x (A 32KB + B 32KB) = 128 KB double buffer + 1 KB bias (gfx950: 160KB/CU)
  __shared__ __align__(16) unsigned short smA[2][256 * 64];
  __shared__ __align__(16) unsigned short smB[2][256 * 64];
  __shared__ float biasLds[256];

  const int tid = threadIdx.x;
  const int wave = tid >> 6;
  const int lane = tid & 63;
  const int quad = lane >> 4;
  const int r16 = lane & 15;
  const int wr = wave >> 2;   // 2 wave-rows
  const int wc = wave & 3;    // 4 wave-cols

  const int rowA0 = blockIdx.x * 256;
  const int rowB0 = blockIdx.y * 256;
  const unsigned short* Ag = A + (size_t)rowA0 * 1024;
  const unsigned short* Bg = Bw + (size_t)rowB0 * 1024;

  if (tid < 256) {
    const int col = rowB0 + tid;
    biasLds[tid] = bias[col] + tval * Wfull[(size_t)col * 1025 + 1024];
  }

  // stage one 128-row half-tile (2 x global_load_lds_dwordx4 per thread),
  // pre-swizzled global source so linear LDS dest == swizzled layout.
  auto stg = [&](const unsigned short* gbase, unsigned short* lds, int k0, int half) {
#pragma unroll
    for (int i = 0; i < 2; ++i) {
      const int s = half * 1024 + i * 512 + tid;   // 16B-chunk index in tile
      const int row = s >> 3;
      const int c = (s & 7) ^ (row & 7);           // inverse swizzle on source
      const unsigned short* g = gbase + (size_t)row * 1024 + (k0 + (c << 3));
      char* l = (char*)lds + (size_t)(half * 1024 + i * 512 + (wave << 6)) * 16;
      async_cp16(g, l);
    }
  };

  f32x4 acc[8][4];
  const f32x4 zero = {0.f, 0.f, 0.f, 0.f};
#pragma unroll
  for (int i = 0; i < 8; ++i)
#pragma unroll
    for (int j = 0; j < 4; ++j) acc[i][j] = zero;

  // prologue: stage tiles 0 (buf0) and 1 (buf1); wait tile0 (8 newest in flight)
  stg(Bg, smB[0], 0, 0);  stg(Bg, smB[0], 0, 1);
  stg(Ag, smA[0], 0, 0);  stg(Ag, smA[0], 0, 1);
  stg(Bg, smB[1], 64, 0); stg(Bg, smB[1], 64, 1);
  stg(Ag, smA[1], 64, 0); stg(Ag, smA[1], 64, 1);
  VBAR8;

  // tiles 0..13: full staging of tile t+2 into the CURRENT buffer
  for (int tt = 0; tt < 14; tt += 2) {
    const int kn0 = (tt + 2) * 64;
    const int kn1 = (tt + 3) * 64;
    TILE(smA[0], smB[0],
         stg(Bg, smB[0], kn0, 0),
         stg(Bg, smB[0], kn0, 1),
         (stg(Ag, smA[0], kn0, 0), stg(Ag, smA[0], kn0, 1)),
         VBAR8)
    TILE(smA[1], smB[1],
         stg(Bg, smB[1], kn1, 0),
         stg(Bg, smB[1], kn1, 1),
         (stg(Ag, smA[1], kn1, 0), stg(Ag, smA[1], kn1, 1)),
         VBAR8)
  }
  // tile 14: nothing left to stage; drain tile 15's loads at the boundary
  TILE(smA[0], smB[0], ;, ;, ;, VBAR0)
  // tile 15: last tile, no boundary needed
  TILE(smA[1], smB[1], ;, ;, ;, ;)

  // epilogue: C/D layout col=lane&15, row=(lane>>4)*4+r ; bias + relu
#pragma unroll
  for (int mt = 0; mt < 8; ++mt) {
    const int grow0 = rowA0 + wr * 128 + mt * 16 + quad * 4;
#pragma unroll
    for (int nt = 0; nt < 4; ++nt) {
      const int lcol = wc * 64 + nt * 16 + r16;
      const int gcol = rowB0 + lcol;
      const float bi = biasLds[lcol];
#pragma unroll
      for (int r = 0; r < 4; ++r) {
        float v = acc[mt][nt][r] + bi;
        v = fmaxf(v, 0.0f);
        Ch[(size_t)(grow0 + r) * 1024 + gcol] = f2h_bits(v);
      }
    }
  }
}

// ---------------------------------------------------------------------------
// Last layer fused with RK4 combine (BM=32, BN=64 full width), dbuf BK=32.
// ---------------------------------------------------------------------------
__launch_bounds__(256, 4)
__global__ void gemm_l4(const unsigned short* __restrict__ A,
                        const unsigned short* __restrict__ Bw,
                        const float* __restrict__ Wfull,
                        const float* __restrict__ bias,
                        float tval,
                        float* __restrict__ y, float* __restrict__ ksum,
                        unsigned short* __restrict__ yh,
                        float* __restrict__ outp, int mode, float dt) {
  constexpr int K = 1024, BK = 32, BM = 32, BN = 64, NI = K / BK;
  __shared__ __align__(16) unsigned short smA[2][BM * BK];
  __shared__ __align__(16) unsigned short smB[2][BN * BK];
  __shared__ float biasLds[BN];

  const int tid = threadIdx.x;
  const int wave = tid >> 6;
  const int lane = tid & 63;
  const int quad = lane >> 4;
  const int r16 = lane & 15;

  const int rowA0 = blockIdx.x * BM;
  const int waveM = wave >> 1;
  const int waveN = wave & 1;

  if (tid < BN) {
    biasLds[tid] = bias[tid] + tval * Wfull[(size_t)tid * (K + 1) + K];
  }

  auto stage = [&](int k0, int buf) {
    if (tid < BM * 4) {
      const int s = tid;
      const int row = s >> 2;
      const int c = (s & 3) ^ ((row >> 1) & 3);
      const unsigned short* g = A + (size_t)(rowA0 + row) * K + (k0 + c * 8);
      char* l = ((char*)smA[buf]) + (size_t)(wave << 6) * 16;
      async_cp16(g, l);
    }
    {
      const int s = tid;
      const int row = s >> 2;
      const int c = (s & 3) ^ ((row >> 1) & 3);
      const unsigned short* g = Bw + (size_t)row * K + (k0 + c * 8);
      char* l = ((char*)smB[buf]) + (size_t)(wave << 6) * 16;
      async_cp16(g, l);
    }
  };

  f32x4 acc[2];
  const f32x4 zero = {0.f, 0.f, 0.f, 0.f};
  acc[0] = zero; acc[1] = zero;

  stage(0, 0);

#pragma unroll 2
  for (int kk = 0; kk < NI; ++kk) {
    __syncthreads();
    if (kk + 1 < NI) stage((kk + 1) * BK, (kk + 1) & 1);

    const unsigned short* sA = smA[kk & 1];
    const unsigned short* sB = smB[kk & 1];
    f16x8 af, bfr[2];
    {
      const int row = waveM * 16 + r16;
      const int cp = quad ^ ((row >> 1) & 3);
      af = *(const f16x8*)(sA + row * BK + cp * 8);
    }
#pragma unroll
    for (int nt = 0; nt < 2; ++nt) {
      const int row = (waveN * 2 + nt) * 16 + r16;
      const int cp = quad ^ ((row >> 1) & 3);
      bfr[nt] = *(const f16x8*)(sB + row * BK + cp * 8);
    }
#pragma unroll
    for (int nt = 0; nt < 2; ++nt)
      acc[nt] = __builtin_amdgcn_mfma_f32_16x16x32_f16(af, bfr[nt], acc[nt], 0, 0, 0);
  }

  const int grow0 = rowA0 + waveM * 16 + quad * 4;
#pragma unroll
  for (int nt = 0; nt < 2; ++nt) {
    const int col = waveN * 32 + nt * 16 + r16;
    const float bi = biasLds[col];
#pragma unroll
    for (int r = 0; r < 4; ++r) {
      const float k = acc[nt][r] + bi;
      const int row = grow0 + r;
      const int idx = row * 64 + col;
      if (mode == 0) {
        ksum[idx] = k;
        yh[idx] = f2h_bits(y[idx] + 0.5f * dt * k);
      } else if (mode == 1) {
        ksum[idx] += 2.f * k;
        yh[idx] = f2h_bits(y[idx] + 0.5f * dt * k);
      } else if (mode == 2) {
        ksum[idx] += 2.f * k;
        yh[idx] = f2h_bits(y[idx] + dt * k);
      } else {
        const float yn = y[idx] + (dt / 6.f) * (ksum[idx] + k);
        y[idx] = yn;
        yh[idx] = f2h_bits(yn);
        if (outp && col < 32) outp[row * 32 + col] = yn;
      }
    }
  }
}

// fp32 W (N x (K+1), time col dropped) -> fp16 Wh (N x K), row-major
__global__ void conv_w(const float* __restrict__ W, unsigned short* __restrict__ Wh,
                       int N, int K) {
  const int idx = blockIdx.x * 256 + threadIdx.x;
  if (idx < N * K) {
    const int n = idx / K;
    const int k = idx - n * K;
    Wh[idx] = f2h_bits(W[(size_t)n * (K + 1) + k]);
  }
}

// y0 = concat(x, aug); row-major fp32 + fp16 copy
__global__ void init_y(const float* __restrict__ x, const float* __restrict__ aug,
                       float* __restrict__ y, unsigned short* __restrict__ yh) {
  const int idx = blockIdx.x * 256 + threadIdx.x;  // BATCH*64
  const int i = idx >> 6;
  const int j = idx & 63;
  const float v = (j < 32) ? x[i * 32 + j] : aug[i * 32 + (j - 32)];
  y[idx] = v;
  yh[idx] = f2h_bits(v);
}

extern "C" void kernel_launch(void* const* d_in, const int* in_sizes, int n_in,
                              void* d_out, int out_size, void* d_ws, size_t ws_size,
                              hipStream_t stream) {
  const float* x = (const float*)d_in[0];
  const float* aug = (const float*)d_in[1];
  const float* W[5];
  const float* b[5];
  for (int i = 0; i < 5; ++i) {
    W[i] = (const float*)d_in[2 + 2 * i];
    b[i] = (const float*)d_in[3 + 2 * i];
  }

  char* ws = (char*)d_ws;
  auto alloc = [&](size_t bytes) -> char* {
    char* p = ws;
    ws += (bytes + 255) & ~(size_t)255;
    return p;
  };
  float* y = (float*)alloc((size_t)BATCH * 64 * 4);
  unsigned short* yh = (unsigned short*)alloc((size_t)BATCH * 64 * 2);
  unsigned short* h1 = (unsigned short*)alloc((size_t)BATCH * 1024 * 2);
  unsigned short* h2 = (unsigned short*)alloc((size_t)BATCH * 1024 * 2);
  float* ksum = (float*)alloc((size_t)BATCH * 64 * 4);
  const int Kdim[5] = {64, 1024, 1024, 1024, 1024};
  const int Ndim[5] = {1024, 1024, 1024, 1024, 64};
  unsigned short* Wh[5];
  for (int i = 0; i < 5; ++i)
    Wh[i] = (unsigned short*)alloc((size_t)Ndim[i] * Kdim[i] * 2);

  for (int i = 0; i < 5; ++i) {
    const int total = Ndim[i] * Kdim[i];
    conv_w<<<(total + 255) / 256, 256, 0, stream>>>(W[i], Wh[i], Ndim[i], Kdim[i]);
  }
  init_y<<<BATCH * 64 / 256, 256, 0, stream>>>(x, aug, y, yh);

  const float dt = 0.125f;
  float* outp = (float*)d_out;

  auto eval = [&](float t, int mode, float* op) {
    // layer 0: [B,64] x [64,1024]^T -> h1  (small-K proven kernel)
    gemm_h<256, 128, 4, 4, 64, 1024, true>
        <<<dim3(BATCH / 256, 1024 / 128), 512, 0, stream>>>(
            yh, Wh[0], W[0], b[0], t, h1);
    unsigned short* src = h1;
    unsigned short* dst = h2;
    for (int L = 1; L <= 3; ++L) {
      gemm8<<<dim3(BATCH / 256, 1024 / 256), 512, 0, stream>>>(
          src, Wh[L], W[L], b[L], t, dst);
      unsigned short* tmp = src; src = dst; dst = tmp;
    }
    gemm_l4<<<dim3(BATCH / 32, 1), 256, 0, stream>>>(
        src, Wh[4], W[4], b[4], t, y, ksum, yh, op, mode, dt);
  };

  for (int s = 0; s < 8; ++s) {
    const float t0 = s * dt;
    eval(t0, 0, nullptr);
    eval(t0 + 0.5f * dt, 1, nullptr);
    eval(t0 + 0.5f * dt, 2, nullptr);
    eval(t0 + dt, 3, (s == 7) ? outp : nullptr);
  }
}